// Round 1
// baseline (356.541 us; speedup 1.0000x reference)
//
#include <hip/hip_runtime.h>

// KL-style loss: mean_n [ -sum_y target[n,y] * log_softmax(pred)[n,y] ]
// N = 4194304 rows, C = 10, fp32 in, scalar fp32 out.
//
// Identity: loss_total = sum_n [ st_n * lse_n ] - sum_{n,y} t*x
//
// R6: register-only row processing. C=10 means 20 contiguous floats
// (5 x float4, 16B-aligned) == exactly 2 complete rows. Loading each
// thread's 5 float4s CONTIGUOUSLY (lane stride 80B) gives it 2 whole rows
// in registers: the entire LDS double-scatter (40 ds_write + 20 ds_read
// per thread), 3 barriers, and the per-element div/mod address math from
// R5 disappear. Each wave's 5-deep unroll covers one contiguous 5120B
// span with every fetched line fully consumed (same lane touches a 64B
// line 4x across the unroll -> L1 absorbs), so HBM efficiency holds.

#define N_ROWS 4194304
#define C_DIM 10
#define BLOCK 256
#define ROWS_PER_THREAD 2
#define ROWS_PER_BLOCK (BLOCK * ROWS_PER_THREAD)       // 512
#define F4_PER_THREAD 5                                // 2 rows * 10 / 4
#define F4_PER_BLOCK (ROWS_PER_BLOCK * C_DIM / 4)      // 1280
#define NBLOCKS (N_ROWS / ROWS_PER_BLOCK)              // 8192
#define RBLOCK 1024

typedef float v4f __attribute__((ext_vector_type(4)));

__global__ __launch_bounds__(BLOCK) void kl_loss_kernel(
    const float* __restrict__ pred,
    const float* __restrict__ tgt,
    float* __restrict__ partial)   // NBLOCKS floats
{
    __shared__ float sred[BLOCK / 64];

    const int tid = threadIdx.x;
    const size_t base_f4 = (size_t)blockIdx.x * F4_PER_BLOCK
                         + (size_t)tid * F4_PER_THREAD;

    const v4f* p4 = reinterpret_cast<const v4f*>(pred);
    const v4f* t4 = reinterpret_cast<const v4f*>(tgt);

    // ---- loads: 2 complete rows per thread, straight into registers ----
    v4f pv[F4_PER_THREAD], tv[F4_PER_THREAD];
#pragma unroll
    for (int i = 0; i < F4_PER_THREAD; ++i)
        pv[i] = __builtin_nontemporal_load(&p4[base_f4 + i]);
#pragma unroll
    for (int i = 0; i < F4_PER_THREAD; ++i)
        tv[i] = __builtin_nontemporal_load(&t4[base_f4 + i]);

    float x[2 * C_DIM], t[2 * C_DIM];
#pragma unroll
    for (int i = 0; i < F4_PER_THREAD; ++i)
#pragma unroll
        for (int c = 0; c < 4; ++c) {
            x[i * 4 + c] = pv[i][c];
            t[i * 4 + c] = tv[i][c];
        }

    // global dot term: no row structure needed
    float dot = 0.0f;
#pragma unroll
    for (int k = 0; k < 2 * C_DIM; ++k)
        dot = fmaf(t[k], x[k], dot);

    // per-row lse and target-sum, entirely in registers
    float acc = -dot;
#pragma unroll
    for (int half = 0; half < 2; ++half) {
        const int o = half * C_DIM;
        float m = x[o];
#pragma unroll
        for (int y = 1; y < C_DIM; ++y) m = fmaxf(m, x[o + y]);
        float s = 0.0f;
#pragma unroll
        for (int y = 0; y < C_DIM; ++y) s += __expf(x[o + y] - m);
        float st = 0.0f;
#pragma unroll
        for (int y = 0; y < C_DIM; ++y) st += t[o + y];
        acc = fmaf(st, m + __logf(s), acc);
    }

    // ---- Reduction: wave shuffle -> LDS -> one store per block ----
#pragma unroll
    for (int off = 32; off > 0; off >>= 1)
        acc += __shfl_down(acc, off, 64);

    const int lane = tid & 63;
    const int wid  = tid >> 6;
    if (lane == 0) sred[wid] = acc;
    __syncthreads();

    if (tid == 0)
        partial[blockIdx.x] = sred[0] + sred[1] + sred[2] + sred[3];
}

// ---------------- final reduce: one block over NBLOCKS partials ----------------
__global__ __launch_bounds__(RBLOCK) void kl_reduce_kernel(
    const float* __restrict__ partial,
    float* __restrict__ out)
{
    __shared__ float sred[RBLOCK / 64];
    const int tid = threadIdx.x;

    float acc = 0.0f;
#pragma unroll
    for (int i = 0; i < NBLOCKS / RBLOCK; ++i)
        acc += partial[i * RBLOCK + tid];

#pragma unroll
    for (int off = 32; off > 0; off >>= 1)
        acc += __shfl_down(acc, off, 64);

    const int lane = tid & 63;
    const int wid  = tid >> 6;
    if (lane == 0) sred[wid] = acc;
    __syncthreads();

    if (tid == 0) {
        float b = 0.0f;
#pragma unroll
        for (int i = 0; i < RBLOCK / 64; ++i) b += sred[i];
        out[0] = b * (1.0f / (float)N_ROWS);
    }
}

extern "C" void kernel_launch(void* const* d_in, const int* in_sizes, int n_in,
                              void* d_out, int out_size, void* d_ws, size_t ws_size,
                              hipStream_t stream)
{
    const float* pred = (const float*)d_in[0];
    const float* tgt  = (const float*)d_in[1];
    float* out = (float*)d_out;
    float* partialbuf = (float*)d_ws;

    kl_loss_kernel<<<NBLOCKS, BLOCK, 0, stream>>>(pred, tgt, partialbuf);
    kl_reduce_kernel<<<1, RBLOCK, 0, stream>>>(partialbuf, out);
}

// Round 2
// 300.335 us; speedup vs baseline: 1.1871x; 1.1871x over previous
//
#include <hip/hip_runtime.h>

// KL-style loss: mean_n [ -sum_y target[n,y] * log_softmax(pred)[n,y] ]
// N = 4194304 rows, C = 10, fp32 in, scalar fp32 out.
//
// Identity: loss_total = sum_n [ st_n * lse_n ] - sum_{n,y} t*x
//
// R7: coalesced loads + vectorized LDS row-gather.
//   R6 lesson: lane-stride-80B loads -> 80 lines/wave-instruction -> request
//   -rate bound at 2.2 TB/s (27% peak) even with zero overfetch. Coalescing
//   is about transactions, not bytes.
//   Here: loads are the canonical i*BLOCK+tid f4 pattern (1024B contiguous
//   per wave-instruction). Row structure is recovered through LDS with
//   all-vector traffic: 5x ds_write_b128 linear (conflict-free), barrier,
//   5x ds_read_b128 of 2 whole rows at byte 80*tid (64 lanes x 16B over a
//   5120B span hits all 32 banks evenly 8-deep = the 1024B/wave size floor,
//   so no effective conflict penalty). 15 LDS ops/array vs R5's 60, and
//   1 barrier vs 3. Compute (dot, lse, st) is all-register per 2 rows.

#define N_ROWS 4194304
#define C_DIM 10
#define BLOCK 256
#define ROWS_PER_BLOCK 512                        // 2 rows per thread
#define F4_PER_THREAD 5                           // 512*10/4/256
#define F4_PER_BLOCK (ROWS_PER_BLOCK * C_DIM / 4) // 1280
#define NBLOCKS (N_ROWS / ROWS_PER_BLOCK)         // 8192
#define RBLOCK 1024

typedef float v4f __attribute__((ext_vector_type(4)));

__global__ __launch_bounds__(BLOCK) void kl_loss_kernel(
    const float* __restrict__ pred,
    const float* __restrict__ tgt,
    float* __restrict__ partial)   // NBLOCKS floats
{
    __shared__ v4f sa[F4_PER_BLOCK];   // pred tile, 20 KB
    __shared__ v4f sb[F4_PER_BLOCK];   // tgt tile, 20 KB
    __shared__ float sred[BLOCK / 64];

    const int tid = threadIdx.x;
    const size_t blk_f4 = (size_t)blockIdx.x * F4_PER_BLOCK;

    const v4f* p4 = reinterpret_cast<const v4f*>(pred);
    const v4f* t4 = reinterpret_cast<const v4f*>(tgt);

    // ---- Phase 1: perfectly coalesced loads (1024B/wave-instruction) ----
    v4f pv[F4_PER_THREAD], tv[F4_PER_THREAD];
#pragma unroll
    for (int i = 0; i < F4_PER_THREAD; ++i)
        pv[i] = __builtin_nontemporal_load(&p4[blk_f4 + i * BLOCK + tid]);
#pragma unroll
    for (int i = 0; i < F4_PER_THREAD; ++i)
        tv[i] = __builtin_nontemporal_load(&t4[blk_f4 + i * BLOCK + tid]);

    // ---- Phase 2: linear vector stage into LDS (conflict-free b128) ----
#pragma unroll
    for (int i = 0; i < F4_PER_THREAD; ++i)
        sa[i * BLOCK + tid] = pv[i];
#pragma unroll
    for (int i = 0; i < F4_PER_THREAD; ++i)
        sb[i * BLOCK + tid] = tv[i];
    __syncthreads();

    // ---- Phase 3: read back 2 whole rows per thread (5x b128 each) ----
    const v4f* ra = reinterpret_cast<const v4f*>(
        reinterpret_cast<const float*>(sa) + 20 * tid);   // byte 80*tid, 16B-aligned
    const v4f* rb = reinterpret_cast<const v4f*>(
        reinterpret_cast<const float*>(sb) + 20 * tid);

    float x[2 * C_DIM], t[2 * C_DIM];
#pragma unroll
    for (int i = 0; i < F4_PER_THREAD; ++i) {
        v4f a = ra[i];
        v4f b = rb[i];
#pragma unroll
        for (int c = 0; c < 4; ++c) {
            x[i * 4 + c] = a[c];
            t[i * 4 + c] = b[c];
        }
    }

    // global dot term (no row structure needed)
    float dot = 0.0f;
#pragma unroll
    for (int k = 0; k < 2 * C_DIM; ++k)
        dot = fmaf(t[k], x[k], dot);

    // per-row lse and target-sum, entirely in registers
    float acc = -dot;
#pragma unroll
    for (int half = 0; half < 2; ++half) {
        const int o = half * C_DIM;
        float m = x[o];
#pragma unroll
        for (int y = 1; y < C_DIM; ++y) m = fmaxf(m, x[o + y]);
        float s = 0.0f;
#pragma unroll
        for (int y = 0; y < C_DIM; ++y) s += __expf(x[o + y] - m);
        float st = 0.0f;
#pragma unroll
        for (int y = 0; y < C_DIM; ++y) st += t[o + y];
        acc = fmaf(st, m + __logf(s), acc);
    }

    // ---- Reduction: wave shuffle -> LDS -> one store per block ----
#pragma unroll
    for (int off = 32; off > 0; off >>= 1)
        acc += __shfl_down(acc, off, 64);

    const int lane = tid & 63;
    const int wid  = tid >> 6;
    if (lane == 0) sred[wid] = acc;
    __syncthreads();

    if (tid == 0)
        partial[blockIdx.x] = sred[0] + sred[1] + sred[2] + sred[3];
}

// ---------------- final reduce: one block over NBLOCKS partials ----------------
__global__ __launch_bounds__(RBLOCK) void kl_reduce_kernel(
    const float* __restrict__ partial,
    float* __restrict__ out)
{
    __shared__ float sred[RBLOCK / 64];
    const int tid = threadIdx.x;

    float acc = 0.0f;
#pragma unroll
    for (int i = 0; i < NBLOCKS / RBLOCK; ++i)
        acc += partial[i * RBLOCK + tid];

#pragma unroll
    for (int off = 32; off > 0; off >>= 1)
        acc += __shfl_down(acc, off, 64);

    const int lane = tid & 63;
    const int wid  = tid >> 6;
    if (lane == 0) sred[wid] = acc;
    __syncthreads();

    if (tid == 0) {
        float b = 0.0f;
#pragma unroll
        for (int i = 0; i < RBLOCK / 64; ++i) b += sred[i];
        out[0] = b * (1.0f / (float)N_ROWS);
    }
}

extern "C" void kernel_launch(void* const* d_in, const int* in_sizes, int n_in,
                              void* d_out, int out_size, void* d_ws, size_t ws_size,
                              hipStream_t stream)
{
    const float* pred = (const float*)d_in[0];
    const float* tgt  = (const float*)d_in[1];
    float* out = (float*)d_out;
    float* partialbuf = (float*)d_ws;

    kl_loss_kernel<<<NBLOCKS, BLOCK, 0, stream>>>(pred, tgt, partialbuf);
    kl_reduce_kernel<<<1, RBLOCK, 0, stream>>>(partialbuf, out);
}